// Round 5
// baseline (408.044 us; speedup 1.0000x reference)
//
#include <hip/hip_runtime.h>
#include <hip/hip_bf16.h>

#define CIN 512
#define OQK 64
#define NBATCH 4
#define NTOK 4096

typedef float f32x4 __attribute__((ext_vector_type(4)));
typedef _Float16 f16x8 __attribute__((ext_vector_type(8)));
typedef short s16x8 __attribute__((ext_vector_type(8)));
typedef unsigned short u16;

__device__ inline u16 f2bf(float f) {
    unsigned u = __float_as_uint(f);
    u += 0x7fffu + ((u >> 16) & 1u);
    return (u16)(u >> 16);
}
__device__ inline u16 f2h_bits(float f) {
    _Float16 h = (_Float16)f;
    return __builtin_bit_cast(unsigned short, h);
}
__device__ inline f16x8 cvt8(const f32x4 a, const f32x4 b) {
    f16x8 r;
    #pragma unroll
    for (int j = 0; j < 4; ++j) { r[j] = (_Float16)a[j]; r[j + 4] = (_Float16)b[j]; }
    return r;
}

// ---------------- Q/K projection + fused x_s copy-out ----------------
__global__ __launch_bounds__(256, 4) void proj_qk(
    const float* __restrict__ x, const float* __restrict__ Wq, const float* __restrict__ bq,
    const float* __restrict__ Wk, const float* __restrict__ bk,
    u16* __restrict__ Qh, u16* __restrict__ Kh, float* __restrict__ out)
{
    const int nb = blockIdx.x;   // 128 blocks of 32 tokens
    const int b  = blockIdx.y;   // 4
    const int tid = threadIdx.x;
    const int w = tid >> 6, l = tid & 63;
    const int lr = l & 15, lg = l >> 4;
    const int qk = w >> 1, half = w & 1;

    const int n = nb * 32 + half * 16 + lr;
    const float* xsrc = x + (size_t)(b + (qk ? NBATCH : 0)) * CIN * NTOK;
    const float* W    = qk ? Wk : Wq;
    const float* bias = qk ? bk : bq;
    u16* outp         = qk ? Kh : Qh;
    float* os         = out + (size_t)b * CIN * NTOK;   // x_s passthrough (Q-waves only)

    f32x4 acc[4] = {};
    for (int t = 0; t < 16; ++t) {
        const int c0 = t * 32 + lg * 8;
        f16x8 A;
        float av[8];
        #pragma unroll
        for (int j = 0; j < 8; ++j) {
            av[j] = xsrc[(size_t)(c0 + j) * NTOK + n];
            A[j] = (_Float16)av[j];
        }
        if (qk == 0) {
            #pragma unroll
            for (int j = 0; j < 8; ++j) os[(size_t)(c0 + j) * NTOK + n] = av[j];
        }
        #pragma unroll
        for (int of = 0; of < 4; ++of) {
            const float* wp = W + (size_t)(of * 16 + lr) * CIN + c0;
            f16x8 B = cvt8(*(const f32x4*)wp, *(const f32x4*)(wp + 4));
            acc[of] = __builtin_amdgcn_mfma_f32_16x16x32_f16(A, B, acc[of], 0, 0, 0);
        }
    }
    #pragma unroll
    for (int of = 0; of < 4; ++of) {
        const int o = of * 16 + lr;
        const float bv_ = bias[o];
        #pragma unroll
        for (int r = 0; r < 4; ++r) {
            const int nn = nb * 32 + half * 16 + lg * 4 + r;
            outp[((size_t)b * NTOK + nn) * OQK + o] = f2h_bits(acc[of][r] + bv_);
        }
    }
}

// ---------------- V projection: V[b][c][m] (bf16) ----------------
__global__ __launch_bounds__(256, 4) void proj_v(
    const float* __restrict__ x, const float* __restrict__ Wv, const float* __restrict__ bv,
    u16* __restrict__ Vb)
{
    const int mb = blockIdx.x;   // 128 blocks of 32 tokens
    const int b  = blockIdx.y;
    const int tid = threadIdx.x;
    const int w = tid >> 6, l = tid & 63;
    const int lr = l & 15, lg = l >> 4;

    const float* xt = x + (size_t)(b + NBATCH) * CIN * NTOK;

    f32x4 acc[8][2] = {};   // [cf][fm]
    for (int t = 0; t < 16; ++t) {
        const int c0 = t * 32 + lg * 8;
        f16x8 Bf[2];
        #pragma unroll
        for (int fm = 0; fm < 2; ++fm) {
            const int mm = mb * 32 + fm * 16 + lr;
            #pragma unroll
            for (int j = 0; j < 8; ++j) Bf[fm][j] = (_Float16)xt[(size_t)(c0 + j) * NTOK + mm];
        }
        #pragma unroll
        for (int cf = 0; cf < 8; ++cf) {
            const int c = w * 128 + cf * 16 + lr;
            const float* wv = Wv + (size_t)c * CIN + c0;
            f16x8 A = cvt8(*(const f32x4*)wv, *(const f32x4*)(wv + 4));
            #pragma unroll
            for (int fm = 0; fm < 2; ++fm)
                acc[cf][fm] = __builtin_amdgcn_mfma_f32_16x16x32_f16(A, Bf[fm], acc[cf][fm], 0, 0, 0);
        }
    }
    #pragma unroll
    for (int cf = 0; cf < 8; ++cf) {
        #pragma unroll
        for (int fm = 0; fm < 2; ++fm) {
            #pragma unroll
            for (int r = 0; r < 4; ++r) {
                const int c  = w * 128 + cf * 16 + lg * 4 + r;
                const int mm = mb * 32 + fm * 16 + lr;
                Vb[((size_t)b * CIN + c) * NTOK + mm] = f2bf(acc[cf][fm][r] + bv[c]);
            }
        }
    }
}

// ---------------- fused attention + residual ----------------
// 512 blocks x 256 threads (4 waves, 32 q-rows). 2 independent blocks/CU so
// barrier stalls of one block are hidden by the other. XCD-pinned batches.
// S-phase: wave w -> rows (w&1)*16..+16, cols ((w>>1)*2 + i)*16.
// PV: wave w -> channels [w*128, w*128+128), all 32 rows.

#define LOADK(mtile, KF)                                                        \
  { _Pragma("unroll")                                                           \
    for (int i_ = 0; i_ < 2; ++i_) {                                            \
      const u16* kp = Kbase + (size_t)((mtile) * 64 + (fmb + i_) * 16 + lr) * OQK + lg * 8; \
      KF[i_][0] = *reinterpret_cast<const f16x8*>(kp);                          \
      KF[i_][1] = *reinterpret_cast<const f16x8*>(kp + 32);                     \
    } }

#define LOADV(mtile)                                                            \
  { _Pragma("unroll")                                                           \
    for (int cf_ = 0; cf_ < 8; ++cf_) {                                         \
      const u16* vp = Vbase + (size_t)(cb + cf_ * 16 + lr) * NTOK + (mtile) * 64 + lg * 8; \
      Vc[cf_][0] = *reinterpret_cast<const s16x8*>(vp);                         \
      Vc[cf_][1] = *reinterpret_cast<const s16x8*>(vp + 32);                    \
    } }

#define SPHASE(KF, PBUF)                                                        \
  { _Pragma("unroll")                                                           \
    for (int i_ = 0; i_ < 2; ++i_) {                                            \
      f32x4 s_ = {};                                                            \
      s_ = __builtin_amdgcn_mfma_f32_16x16x32_f16(Aq0, KF[i_][0], s_, 0, 0, 0); \
      s_ = __builtin_amdgcn_mfma_f32_16x16x32_f16(Aq1, KF[i_][1], s_, 0, 0, 0); \
      _Pragma("unroll")                                                         \
      for (int r_ = 0; r_ < 4; ++r_) {                                          \
        float p_ = __expf(s_[r_]);                                              \
        den[r_] += p_;                                                          \
        const int row_ = fn * 16 + lg * 4 + r_;                                 \
        const int col_ = (fmb + i_) * 16 + lr;                                  \
        Pt[(PBUF) * 2048 + row_ * 64 + (col_ ^ ((row_ & 7) << 3))] = f2bf(p_);  \
      } } }

#define BODY(CUR, KFN, KFC, mt)                                                 \
  {                                                                             \
    asm volatile("s_waitcnt lgkmcnt(0)" ::: "memory");                          \
    __builtin_amdgcn_s_barrier();                                               \
    s16x8 Pa[2][2];                                                             \
    _Pragma("unroll")                                                           \
    for (int a_ = 0; a_ < 2; ++a_) {                                            \
      const int row_ = a_ * 16 + lr;                                            \
      const int sw_ = (row_ & 7) << 3;                                          \
      Pa[a_][0] = *(const s16x8*)&Pt[(CUR) * 2048 + row_ * 64 + ((lg * 8) ^ sw_)];        \
      Pa[a_][1] = *(const s16x8*)&Pt[(CUR) * 2048 + row_ * 64 + ((32 + lg * 8) ^ sw_)];   \
    }                                                                           \
    if ((mt) < 63) {                                                            \
      SPHASE(KFN, (CUR) ^ 1);                                                   \
      if ((mt) < 62) LOADK((mt) + 2, KFC);                                      \
    }                                                                           \
    __builtin_amdgcn_s_setprio(1);                                              \
    _Pragma("unroll")                                                           \
    for (int cf_ = 0; cf_ < 8; ++cf_) {                                         \
      _Pragma("unroll")                                                         \
      for (int a_ = 0; a_ < 2; ++a_)                                            \
        acc[a_][cf_] = __builtin_amdgcn_mfma_f32_16x16x32_bf16(Pa[a_][0], Vc[cf_][0], acc[a_][cf_], 0, 0, 0); \
      _Pragma("unroll")                                                         \
      for (int a_ = 0; a_ < 2; ++a_)                                            \
        acc[a_][cf_] = __builtin_amdgcn_mfma_f32_16x16x32_bf16(Pa[a_][1], Vc[cf_][1], acc[a_][cf_], 0, 0, 0); \
    }                                                                           \
    __builtin_amdgcn_s_setprio(0);                                              \
    if ((mt) < 63) LOADV((mt) + 1);                                             \
  }

__global__ __launch_bounds__(256, 2) void attn(
    const float* __restrict__ x, const u16* __restrict__ Qh, const u16* __restrict__ Kh,
    const u16* __restrict__ Vb, float* __restrict__ out)
{
    __shared__ u16 Pt[2 * 2048];
    __shared__ float den_lds[32];

    const int g = blockIdx.x;
    const int xcd = g & 7;
    const int b = xcd >> 1;                       // batch -> XCD pair
    const int nb = ((g >> 3) << 1) | (xcd & 1);   // 32-row q-block (0..127)

    const int tid = threadIdx.x;
    const int w = tid >> 6, l = tid & 63;
    const int lr = l & 15, lg = l >> 4;
    const int fn = w & 1, fmb = (w >> 1) * 2;     // S-phase role
    const int cb = w * 128;                       // PV role: channel base

    if (tid < 32) den_lds[tid] = 0.f;

    // hoisted Q A-fragments
    f16x8 Aq0, Aq1;
    {
        const u16* qp = Qh + ((size_t)b * NTOK + nb * 32 + fn * 16 + lr) * OQK + lg * 8;
        Aq0 = *reinterpret_cast<const f16x8*>(qp);
        Aq1 = *reinterpret_cast<const f16x8*>(qp + 32);
    }

    f32x4 acc[2][8] = {};                         // [row-frag a][chan-frag cf]
    float den[4] = {0.f, 0.f, 0.f, 0.f};
    const u16* Kbase = Kh + (size_t)b * NTOK * OQK;
    const u16* Vbase = Vb + (size_t)b * CIN * NTOK;

    f16x8 KfA[2][2], KfB[2][2];   // K double buffer (static-indexed)
    s16x8 Vc[8][2];               // V single buffer (reloaded after PV)

    // prologue
    LOADK(0, KfA);
    LOADV(0);
    SPHASE(KfA, 0);
    LOADK(1, KfB);

    for (int mt2 = 0; mt2 < 64; mt2 += 2) {
        BODY(0, KfB, KfA, mt2);
        BODY(1, KfA, KfB, mt2 + 1);
    }

    // ---- denominator reduce ----
    #pragma unroll
    for (int r = 0; r < 4; ++r) {
        float d = den[r];
        d += __shfl_xor(d, 1);
        d += __shfl_xor(d, 2);
        d += __shfl_xor(d, 4);
        d += __shfl_xor(d, 8);
        den[r] = d;
    }
    if (lr == 0) {
        #pragma unroll
        for (int r = 0; r < 4; ++r)
            atomicAdd(&den_lds[fn * 16 + lg * 4 + r], den[r]);
    }
    __syncthreads();

    // ---- epilogue: out = x_t + acc/den ----
    float inv[2][4];
    #pragma unroll
    for (int a = 0; a < 2; ++a) {
        #pragma unroll
        for (int r = 0; r < 4; ++r)
            inv[a][r] = 1.0f / den_lds[a * 16 + lg * 4 + r];
    }
    const float* xtp = x + (size_t)(b + NBATCH) * CIN * NTOK;
    float* op = out + (size_t)(b + NBATCH) * CIN * NTOK;
    #pragma unroll
    for (int a = 0; a < 2; ++a) {
        #pragma unroll
        for (int cf = 0; cf < 8; ++cf) {
            const int c = cb + cf * 16 + lr;
            const size_t base = (size_t)c * NTOK + nb * 32 + a * 16 + lg * 4;
            f32x4 xv = *reinterpret_cast<const f32x4*>(xtp + base);
            f32x4 o;
            #pragma unroll
            for (int r = 0; r < 4; ++r) o[r] = xv[r] + acc[a][cf][r] * inv[a][r];
            *reinterpret_cast<f32x4*>(op + base) = o;
        }
    }
}

extern "C" void kernel_launch(void* const* d_in, const int* in_sizes, int n_in,
                              void* d_out, int out_size, void* d_ws, size_t ws_size,
                              hipStream_t stream)
{
    (void)in_sizes; (void)n_in; (void)out_size; (void)ws_size;
    const float* x  = (const float*)d_in[0];
    const float* Wq = (const float*)d_in[1];
    const float* bq = (const float*)d_in[2];
    const float* Wk = (const float*)d_in[3];
    const float* bk = (const float*)d_in[4];
    const float* Wv = (const float*)d_in[5];
    const float* bv = (const float*)d_in[6];
    float* out = (float*)d_out;

    u16* Qh = (u16*)d_ws;                                   // 4*4096*64 f16
    u16* Kh = Qh + (size_t)NBATCH * NTOK * OQK;             // 4*4096*64 f16
    u16* Vb = Kh + (size_t)NBATCH * NTOK * OQK;             // 4*512*4096 bf16

    proj_qk<<<dim3(128, NBATCH), 256, 0, stream>>>(x, Wq, bq, Wk, bk, Qh, Kh, out);
    proj_v <<<dim3(128, NBATCH), 256, 0, stream>>>(x, Wv, bv, Vb);
    attn   <<<512, 256, 0, stream>>>(x, Qh, Kh, Vb, out);
}

// Round 6
// 404.973 us; speedup vs baseline: 1.0076x; 1.0076x over previous
//
#include <hip/hip_runtime.h>
#include <hip/hip_bf16.h>

#define CIN 512
#define OQK 64
#define NBATCH 4
#define NTOK 4096

typedef float f32x4 __attribute__((ext_vector_type(4)));
typedef _Float16 f16x8 __attribute__((ext_vector_type(8)));
typedef short s16x8 __attribute__((ext_vector_type(8)));
typedef unsigned short u16;
typedef unsigned int u32;
typedef u32 u32x2 __attribute__((ext_vector_type(2)));

__device__ inline u16 f2bf(float f) {
    unsigned u = __float_as_uint(f);
    u += 0x7fffu + ((u >> 16) & 1u);
    return (u16)(u >> 16);
}
__device__ inline u16 f2h_bits(float f) {
    _Float16 h = (_Float16)f;
    return __builtin_bit_cast(unsigned short, h);
}
__device__ inline f16x8 cvt8(const f32x4 a, const f32x4 b) {
    f16x8 r;
    #pragma unroll
    for (int j = 0; j < 4; ++j) { r[j] = (_Float16)a[j]; r[j + 4] = (_Float16)b[j]; }
    return r;
}

// ---------------- fused Q/K/V projections + x_s passthrough ----------------
// 8 waves: 0-1 Q (+x_s copy), 2-3 K, 4-7 V. x_t panel read shared via L2.
__global__ __launch_bounds__(512, 2) void proj_all(
    const float* __restrict__ x,
    const float* __restrict__ Wq, const float* __restrict__ bq,
    const float* __restrict__ Wk, const float* __restrict__ bk,
    const float* __restrict__ Wv, const float* __restrict__ bv,
    u16* __restrict__ Qh, u16* __restrict__ Kh, u16* __restrict__ Vb,
    float* __restrict__ out)
{
    const int nb = blockIdx.x;   // 128 panels of 32 tokens
    const int b  = blockIdx.y;   // 4
    const int tid = threadIdx.x;
    const int w = tid >> 6, l = tid & 63;
    const int lr = l & 15, lg = l >> 4;

    if (w < 4) {
        const int qk = w >> 1, half = w & 1;
        const int n = nb * 32 + half * 16 + lr;
        const float* xsrc = x + (size_t)(b + (qk ? NBATCH : 0)) * CIN * NTOK;
        const float* W    = qk ? Wk : Wq;
        const float* bias = qk ? bk : bq;
        u16* outp         = qk ? Kh : Qh;
        float* os         = out + (size_t)b * CIN * NTOK;

        f32x4 acc[4] = {};
        for (int t = 0; t < 16; ++t) {
            const int c0 = t * 32 + lg * 8;
            f16x8 A; float av[8];
            #pragma unroll
            for (int j = 0; j < 8; ++j) {
                av[j] = xsrc[(size_t)(c0 + j) * NTOK + n];
                A[j] = (_Float16)av[j];
            }
            if (qk == 0) {
                #pragma unroll
                for (int j = 0; j < 8; ++j) os[(size_t)(c0 + j) * NTOK + n] = av[j];
            }
            #pragma unroll
            for (int of = 0; of < 4; ++of) {
                const float* wp = W + (size_t)(of * 16 + lr) * CIN + c0;
                f16x8 B = cvt8(*(const f32x4*)wp, *(const f32x4*)(wp + 4));
                acc[of] = __builtin_amdgcn_mfma_f32_16x16x32_f16(A, B, acc[of], 0, 0, 0);
            }
        }
        #pragma unroll
        for (int of = 0; of < 4; ++of) {
            const int o = of * 16 + lr;
            const float bb_ = bias[o];
            #pragma unroll
            for (int r = 0; r < 4; ++r) {
                const int nn = nb * 32 + half * 16 + lg * 4 + r;
                outp[((size_t)b * NTOK + nn) * OQK + o] = f2h_bits(acc[of][r] + bb_);
            }
        }
    } else {
        const int wv = w - 4;
        const float* xt = x + (size_t)(b + NBATCH) * CIN * NTOK;
        f32x4 acc[8][2] = {};
        for (int t = 0; t < 16; ++t) {
            const int c0 = t * 32 + lg * 8;
            f16x8 Bf[2];
            #pragma unroll
            for (int fm = 0; fm < 2; ++fm) {
                const int mm = nb * 32 + fm * 16 + lr;
                #pragma unroll
                for (int j = 0; j < 8; ++j) Bf[fm][j] = (_Float16)xt[(size_t)(c0 + j) * NTOK + mm];
            }
            #pragma unroll
            for (int cf = 0; cf < 8; ++cf) {
                const int c = wv * 128 + cf * 16 + lr;
                const float* wp = Wv + (size_t)c * CIN + c0;
                f16x8 A = cvt8(*(const f32x4*)wp, *(const f32x4*)(wp + 4));
                #pragma unroll
                for (int fm = 0; fm < 2; ++fm)
                    acc[cf][fm] = __builtin_amdgcn_mfma_f32_16x16x32_f16(A, Bf[fm], acc[cf][fm], 0, 0, 0);
            }
        }
        #pragma unroll
        for (int cf = 0; cf < 8; ++cf) {
            #pragma unroll
            for (int fm = 0; fm < 2; ++fm) {
                #pragma unroll
                for (int r = 0; r < 4; ++r) {
                    const int c  = wv * 128 + cf * 16 + lg * 4 + r;
                    const int mm = nb * 32 + fm * 16 + lr;
                    Vb[((size_t)b * CIN + c) * NTOK + mm] = f2bf(acc[cf][fm][r] + bv[c]);
                }
            }
        }
    }
}

// ---------------- pass S: P = exp(K Q^T) (bf16, [b][n][m]) + exact den ----------------
// 256 blocks (1/CU, XCD-pinned), 4 independent waves x 16 rows. No barriers/LDS.
// Swapped operands (A=K rows=m, B=Q cols=n): lane's 4 acc values are m-contiguous
// -> packed 8-byte P stores. den per row via lg-group shfl reduce (no atomics).

#define SLOADK(mt, KF)                                                          \
  { _Pragma("unroll")                                                           \
    for (int mf_ = 0; mf_ < 4; ++mf_) {                                         \
      const u16* kp = Kbase + (size_t)((mt) * 64 + mf_ * 16 + lr) * OQK + lg * 8; \
      KF[mf_][0] = *reinterpret_cast<const f16x8*>(kp);                         \
      KF[mf_][1] = *reinterpret_cast<const f16x8*>(kp + 32);                    \
    } }

#define STILE(mt, KF)                                                           \
  { _Pragma("unroll")                                                           \
    for (int mf_ = 0; mf_ < 4; ++mf_) {                                         \
      f32x4 s_ = {};                                                            \
      s_ = __builtin_amdgcn_mfma_f32_16x16x32_f16(KF[mf_][0], Bq0, s_, 0, 0, 0);\
      s_ = __builtin_amdgcn_mfma_f32_16x16x32_f16(KF[mf_][1], Bq1, s_, 0, 0, 0);\
      float p0 = __expf(s_[0]), p1 = __expf(s_[1]);                             \
      float p2 = __expf(s_[2]), p3 = __expf(s_[3]);                             \
      denl += (p0 + p1) + (p2 + p3);                                            \
      u32x2 pk;                                                                 \
      pk[0] = (u32)f2bf(p0) | ((u32)f2bf(p1) << 16);                            \
      pk[1] = (u32)f2bf(p2) | ((u32)f2bf(p3) << 16);                            \
      *reinterpret_cast<u32x2*>(Pp + (size_t)n * NTOK + (mt) * 64 + mf_ * 16 + lg * 4) = pk; \
    } }

__global__ __launch_bounds__(256, 2) void qk_exp(
    const u16* __restrict__ Qh, const u16* __restrict__ Kh,
    u16* __restrict__ P, float* __restrict__ den)
{
    const int g = blockIdx.x;
    const int xcd = g & 7;
    const int b = xcd >> 1;
    const int nb = ((g >> 3) << 1) | (xcd & 1);   // 64-row panel (0..63)

    const int tid = threadIdx.x;
    const int w = tid >> 6, l = tid & 63;
    const int lr = l & 15, lg = l >> 4;

    const int n = nb * 64 + w * 16 + lr;          // this lane's output row (as B-col)
    const u16* Kbase = Kh + (size_t)b * NTOK * OQK;
    u16* Pp = P + (size_t)b * NTOK * NTOK;

    // hoisted Q B-fragments
    f16x8 Bq0, Bq1;
    {
        const u16* qp = Qh + ((size_t)b * NTOK + n) * OQK + lg * 8;
        Bq0 = *reinterpret_cast<const f16x8*>(qp);
        Bq1 = *reinterpret_cast<const f16x8*>(qp + 32);
    }

    float denl = 0.f;
    f16x8 KfA[4][2], KfB[4][2];

    SLOADK(0, KfA);
    for (int mt = 0; mt < 64; mt += 2) {
        SLOADK(mt + 1, KfB);
        STILE(mt, KfA);
        if (mt + 2 < 64) SLOADK(mt + 2, KfA);
        STILE(mt + 1, KfB);
    }

    // den: reduce partials across lg groups (same n = lr)
    denl += __shfl_xor(denl, 16);
    denl += __shfl_xor(denl, 32);
    if (l < 16) den[(size_t)b * NTOK + nb * 64 + w * 16 + l] = denl;
}

// ---------------- pass PV: out = x_t + (V P^T) / den ----------------
// 512 blocks (2/CU, XCD-pinned), 4 waves as 2x2, wave tile 64ch x 64n,
// K=4096 streamed with static double-buffered fragments. No barriers/LDS.

#define PVLOAD(m0, VA, PB)                                                      \
  { _Pragma("unroll")                                                           \
    for (int cf_ = 0; cf_ < 4; ++cf_) {                                         \
      const u16* vp = Vba + (size_t)(cbase + cf_ * 16 + lr) * NTOK + (m0) + lg * 8; \
      VA[cf_][0] = *reinterpret_cast<const s16x8*>(vp);                         \
      VA[cf_][1] = *reinterpret_cast<const s16x8*>(vp + 32);                    \
    }                                                                           \
    _Pragma("unroll")                                                           \
    for (int nf_ = 0; nf_ < 4; ++nf_) {                                         \
      const u16* pp = Pba + (size_t)(nbase + nf_ * 16 + lr) * NTOK + (m0) + lg * 8; \
      PB[nf_][0] = *reinterpret_cast<const s16x8*>(pp);                         \
      PB[nf_][1] = *reinterpret_cast<const s16x8*>(pp + 32);                    \
    } }

#define PVMMA(VA, PB)                                                           \
  { __builtin_amdgcn_s_setprio(1);                                              \
    _Pragma("unroll")                                                           \
    for (int cf_ = 0; cf_ < 4; ++cf_) {                                         \
      _Pragma("unroll")                                                         \
      for (int nf_ = 0; nf_ < 4; ++nf_)                                         \
        acc[cf_][nf_] = __builtin_amdgcn_mfma_f32_16x16x32_bf16(VA[cf_][0], PB[nf_][0], acc[cf_][nf_], 0, 0, 0); \
    }                                                                           \
    _Pragma("unroll")                                                           \
    for (int cf_ = 0; cf_ < 4; ++cf_) {                                         \
      _Pragma("unroll")                                                         \
      for (int nf_ = 0; nf_ < 4; ++nf_)                                         \
        acc[cf_][nf_] = __builtin_amdgcn_mfma_f32_16x16x32_bf16(VA[cf_][1], PB[nf_][1], acc[cf_][nf_], 0, 0, 0); \
    }                                                                           \
    __builtin_amdgcn_s_setprio(0); }

__global__ __launch_bounds__(256, 2) void pv(
    const float* __restrict__ x, const u16* __restrict__ Vb,
    const u16* __restrict__ P, const float* __restrict__ den,
    float* __restrict__ out)
{
    const int g = blockIdx.x;
    const int xcd = g & 7;
    const int b = xcd >> 1;
    const int idx = ((g >> 3) << 1) | (xcd & 1);  // 0..127 per batch
    const int bm = idx >> 5;                      // 4 channel blocks of 128
    const int bn = idx & 31;                      // 32 row blocks of 128

    const int tid = threadIdx.x;
    const int w = tid >> 6, l = tid & 63;
    const int lr = l & 15, lg = l >> 4;
    const int wr = w >> 1, wc = w & 1;

    const int cbase = bm * 128 + wr * 64;
    const int nbase = bn * 128 + wc * 64;

    const u16* Vba = Vb + (size_t)b * CIN * NTOK;
    const u16* Pba = P + (size_t)b * NTOK * NTOK;

    f32x4 acc[4][4] = {};                         // [chan-frag][row-frag]
    s16x8 VaA[4][2], VaB[4][2], PbA[4][2], PbB[4][2];

    PVLOAD(0, VaA, PbA);
    for (int m0 = 0; m0 < NTOK; m0 += 128) {
        PVLOAD(m0 + 64, VaB, PbB);
        PVMMA(VaA, PbA);
        if (m0 + 128 < NTOK) PVLOAD(m0 + 128, VaA, PbA);
        PVMMA(VaB, PbB);
    }

    // epilogue: out = x_t + acc / den[n]
    const float* denb = den + (size_t)b * NTOK;
    float inv[4];
    #pragma unroll
    for (int nf = 0; nf < 4; ++nf) inv[nf] = 1.0f / denb[nbase + nf * 16 + lr];

    const float* xtp = x + (size_t)(b + NBATCH) * CIN * NTOK;
    float* op = out + (size_t)(b + NBATCH) * CIN * NTOK;
    #pragma unroll
    for (int cf = 0; cf < 4; ++cf) {
        #pragma unroll
        for (int nf = 0; nf < 4; ++nf) {
            #pragma unroll
            for (int r = 0; r < 4; ++r) {
                const int c = cbase + cf * 16 + lg * 4 + r;
                const int n = nbase + nf * 16 + lr;
                const size_t idx2 = (size_t)c * NTOK + n;
                op[idx2] = xtp[idx2] + acc[cf][nf][r] * inv[nf];
            }
        }
    }
}

extern "C" void kernel_launch(void* const* d_in, const int* in_sizes, int n_in,
                              void* d_out, int out_size, void* d_ws, size_t ws_size,
                              hipStream_t stream)
{
    (void)in_sizes; (void)n_in; (void)out_size; (void)ws_size;
    const float* x  = (const float*)d_in[0];
    const float* Wq = (const float*)d_in[1];
    const float* bq = (const float*)d_in[2];
    const float* Wk = (const float*)d_in[3];
    const float* bk = (const float*)d_in[4];
    const float* Wv = (const float*)d_in[5];
    const float* bv = (const float*)d_in[6];
    float* out = (float*)d_out;

    // ws layout (total ~148.1 MB): Qh 2MB | Kh 2MB | Vb 16MB | den 64KB | P 128MB
    u16* Qh = (u16*)d_ws;
    u16* Kh = Qh + (size_t)NBATCH * NTOK * OQK;
    u16* Vb = Kh + (size_t)NBATCH * NTOK * OQK;
    float* den = (float*)(Vb + (size_t)NBATCH * CIN * NTOK);
    u16* P  = (u16*)(den + (size_t)NBATCH * NTOK);

    proj_all<<<dim3(128, NBATCH), 512, 0, stream>>>(x, Wq, bq, Wk, bk, Wv, bv, Qh, Kh, Vb, out);
    qk_exp <<<256, 256, 0, stream>>>(Qh, Kh, P, den);
    pv     <<<512, 256, 0, stream>>>(x, Vb, P, den, out);
}

// Round 7
// 274.068 us; speedup vs baseline: 1.4888x; 1.4776x over previous
//
#include <hip/hip_runtime.h>
#include <hip/hip_bf16.h>

#define CIN 512
#define OQK 64
#define NBATCH 4
#define NTOK 4096

typedef float f32x4 __attribute__((ext_vector_type(4)));
typedef _Float16 f16x8 __attribute__((ext_vector_type(8)));
typedef short s16x8 __attribute__((ext_vector_type(8)));
typedef unsigned short u16;
typedef unsigned int u32;
typedef u32 u32x2 __attribute__((ext_vector_type(2)));

__device__ inline u16 f2bf(float f) {
    unsigned u = __float_as_uint(f);
    u += 0x7fffu + ((u >> 16) & 1u);
    return (u16)(u >> 16);
}
__device__ inline u16 f2h_bits(float f) {
    _Float16 h = (_Float16)f;
    return __builtin_bit_cast(unsigned short, h);
}
__device__ inline f16x8 cvt8(const f32x4 a, const f32x4 b) {
    f16x8 r;
    #pragma unroll
    for (int j = 0; j < 4; ++j) { r[j] = (_Float16)a[j]; r[j + 4] = (_Float16)b[j]; }
    return r;
}

#define GLOAD16(gp, lp) __builtin_amdgcn_global_load_lds(                        \
    (const __attribute__((address_space(1))) void*)(gp),                         \
    (__attribute__((address_space(3))) void*)(lp), 16, 0, 0)

// ---------------- fused Q/K/V projections + x_s passthrough ----------------
__global__ __launch_bounds__(512, 2) void proj_all(
    const float* __restrict__ x,
    const float* __restrict__ Wq, const float* __restrict__ bq,
    const float* __restrict__ Wk, const float* __restrict__ bk,
    const float* __restrict__ Wv, const float* __restrict__ bv,
    u16* __restrict__ Qh, u16* __restrict__ Kh, u16* __restrict__ Vb,
    float* __restrict__ out)
{
    const int nb = blockIdx.x;   // 128 panels of 32 tokens
    const int b  = blockIdx.y;   // 4
    const int tid = threadIdx.x;
    const int w = tid >> 6, l = tid & 63;
    const int lr = l & 15, lg = l >> 4;

    if (w < 4) {
        const int qk = w >> 1, half = w & 1;
        const int n = nb * 32 + half * 16 + lr;
        const float* xsrc = x + (size_t)(b + (qk ? NBATCH : 0)) * CIN * NTOK;
        const float* W    = qk ? Wk : Wq;
        const float* bias = qk ? bk : bq;
        u16* outp         = qk ? Kh : Qh;
        float* os         = out + (size_t)b * CIN * NTOK;

        f32x4 acc[4] = {};
        for (int t = 0; t < 16; ++t) {
            const int c0 = t * 32 + lg * 8;
            f16x8 A; float av[8];
            #pragma unroll
            for (int j = 0; j < 8; ++j) {
                av[j] = xsrc[(size_t)(c0 + j) * NTOK + n];
                A[j] = (_Float16)av[j];
            }
            if (qk == 0) {
                #pragma unroll
                for (int j = 0; j < 8; ++j) os[(size_t)(c0 + j) * NTOK + n] = av[j];
            }
            #pragma unroll
            for (int of = 0; of < 4; ++of) {
                const float* wp = W + (size_t)(of * 16 + lr) * CIN + c0;
                f16x8 B = cvt8(*(const f32x4*)wp, *(const f32x4*)(wp + 4));
                acc[of] = __builtin_amdgcn_mfma_f32_16x16x32_f16(A, B, acc[of], 0, 0, 0);
            }
        }
        #pragma unroll
        for (int of = 0; of < 4; ++of) {
            const int o = of * 16 + lr;
            const float bb_ = bias[o];
            #pragma unroll
            for (int r = 0; r < 4; ++r) {
                const int nn = nb * 32 + half * 16 + lg * 4 + r;
                outp[((size_t)b * NTOK + nn) * OQK + o] = f2h_bits(acc[of][r] + bb_);
            }
        }
    } else {
        const int wv = w - 4;
        const float* xt = x + (size_t)(b + NBATCH) * CIN * NTOK;
        f32x4 acc[8][2] = {};
        for (int t = 0; t < 16; ++t) {
            const int c0 = t * 32 + lg * 8;
            f16x8 Bf[2];
            #pragma unroll
            for (int fm = 0; fm < 2; ++fm) {
                const int mm = nb * 32 + fm * 16 + lr;
                #pragma unroll
                for (int j = 0; j < 8; ++j) Bf[fm][j] = (_Float16)xt[(size_t)(c0 + j) * NTOK + mm];
            }
            #pragma unroll
            for (int cf = 0; cf < 8; ++cf) {
                const int c = wv * 128 + cf * 16 + lr;
                const float* wp = Wv + (size_t)c * CIN + c0;
                f16x8 A = cvt8(*(const f32x4*)wp, *(const f32x4*)(wp + 4));
                #pragma unroll
                for (int fm = 0; fm < 2; ++fm)
                    acc[cf][fm] = __builtin_amdgcn_mfma_f32_16x16x32_f16(A, Bf[fm], acc[cf][fm], 0, 0, 0);
            }
        }
        #pragma unroll
        for (int cf = 0; cf < 8; ++cf) {
            #pragma unroll
            for (int fm = 0; fm < 2; ++fm) {
                #pragma unroll
                for (int r = 0; r < 4; ++r) {
                    const int c  = wv * 128 + cf * 16 + lg * 4 + r;
                    const int mm = nb * 32 + fm * 16 + lr;
                    Vb[((size_t)b * CIN + c) * NTOK + mm] = f2bf(acc[cf][fm][r] + bv[c]);
                }
            }
        }
    }
}

// ---------------- pass S: P = exp(K Q^T) (bf16, [b][n][m]) + exact den ----------------
// 1024 blocks x 256 thr, 16 waves/CU. Block = 16 q-rows; wave w owns m-quarter.
// den combined across the 4 waves via LDS.

#define SLOADK(mt, KF)                                                          \
  { _Pragma("unroll")                                                           \
    for (int mf_ = 0; mf_ < 4; ++mf_) {                                         \
      const u16* kp = Kbase + (size_t)((mt) * 64 + mf_ * 16 + lr) * OQK + lg * 8; \
      KF[mf_][0] = *reinterpret_cast<const f16x8*>(kp);                         \
      KF[mf_][1] = *reinterpret_cast<const f16x8*>(kp + 32);                    \
    } }

#define STILE(mt, KF)                                                           \
  { _Pragma("unroll")                                                           \
    for (int mf_ = 0; mf_ < 4; ++mf_) {                                         \
      f32x4 s_ = {};                                                            \
      s_ = __builtin_amdgcn_mfma_f32_16x16x32_f16(KF[mf_][0], Bq0, s_, 0, 0, 0);\
      s_ = __builtin_amdgcn_mfma_f32_16x16x32_f16(KF[mf_][1], Bq1, s_, 0, 0, 0);\
      float p0 = __expf(s_[0]), p1 = __expf(s_[1]);                             \
      float p2 = __expf(s_[2]), p3 = __expf(s_[3]);                             \
      denl += (p0 + p1) + (p2 + p3);                                            \
      u32x2 pk;                                                                 \
      pk[0] = (u32)f2bf(p0) | ((u32)f2bf(p1) << 16);                            \
      pk[1] = (u32)f2bf(p2) | ((u32)f2bf(p3) << 16);                            \
      *reinterpret_cast<u32x2*>(Pp + (size_t)n * NTOK + (mt) * 64 + mf_ * 16 + lg * 4) = pk; \
    } }

__global__ __launch_bounds__(256, 4) void qk_exp(
    const u16* __restrict__ Qh, const u16* __restrict__ Kh,
    u16* __restrict__ P, float* __restrict__ den)
{
    __shared__ float dpart[4][16];
    const int g = blockIdx.x;
    const int xcd = g & 7;
    const int b = xcd >> 1;
    const int grp = ((g >> 3) << 1) | (xcd & 1);   // 16-row group (0..255)

    const int tid = threadIdx.x;
    const int w = tid >> 6, l = tid & 63;
    const int lr = l & 15, lg = l >> 4;

    const int n = grp * 16 + lr;
    const int mbase = w * 1024;                    // wave's m-quarter
    const u16* Kbase = Kh + ((size_t)b * NTOK + mbase) * OQK;
    u16* Pp = P + (size_t)b * NTOK * NTOK + mbase;

    f16x8 Bq0, Bq1;
    {
        const u16* qp = Qh + ((size_t)b * NTOK + n) * OQK + lg * 8;
        Bq0 = *reinterpret_cast<const f16x8*>(qp);
        Bq1 = *reinterpret_cast<const f16x8*>(qp + 32);
    }

    float denl = 0.f;
    f16x8 KfA[4][2], KfB[4][2];

    SLOADK(0, KfA);
    for (int mt = 0; mt < 16; mt += 2) {
        SLOADK(mt + 1, KfB);
        STILE(mt, KfA);
        if (mt + 2 < 16) SLOADK(mt + 2, KfA);
        STILE(mt + 1, KfB);
    }

    denl += __shfl_xor(denl, 16);
    denl += __shfl_xor(denl, 32);
    if (l < 16) dpart[w][l] = denl;
    __syncthreads();
    if (tid < 16)
        den[(size_t)b * NTOK + grp * 16 + tid] =
            (dpart[0][tid] + dpart[1][tid]) + (dpart[2][tid] + dpart[3][tid]);
}

// ---------------- pass PV: out = x_t + (V P^T) / den ----------------
// m97-style LDS-staged GEMM. Tile 128c x 64n, BK=32, double-buffered LDS via
// global_load_lds (linear dest, pre-swizzled source), 2-barrier K-loop.
// 1024 blocks x 4 waves, 4 blocks/CU (16 waves/CU). Wave = 64c x 32n.

#define PVSTAGE(BUF, m0)                                                        \
  { _Pragma("unroll")                                                           \
    for (int i_ = 0; i_ < 2; ++i_) {                                            \
      const int seg_ = i_ * 4 + w;                                              \
      const int chunk_ = seg_ * 64 + l;                                         \
      const int rowA_ = chunk_ >> 2;                                            \
      const int scA_ = (chunk_ & 3) ^ (rowA_ & 3);                              \
      GLOAD16(Abase + (size_t)rowA_ * NTOK + (m0) + scA_ * 8, &As[BUF][seg_ * 512]); \
    }                                                                           \
    { const int chunk_ = w * 64 + l;                                            \
      const int rowB_ = chunk_ >> 2;                                            \
      const int scB_ = (chunk_ & 3) ^ (rowB_ & 3);                              \
      GLOAD16(Bbase + (size_t)rowB_ * NTOK + (m0) + scB_ * 8, &Bs[BUF][w * 512]); } }

__global__ __launch_bounds__(256, 4) void pv(
    const float* __restrict__ x, const u16* __restrict__ Vb,
    const u16* __restrict__ P, const float* __restrict__ den,
    float* __restrict__ out)
{
    __shared__ u16 As[2][128 * 32];   // V tile  (8 KB per buf)
    __shared__ u16 Bs[2][64 * 32];    // P tile  (4 KB per buf)

    const int g = blockIdx.x;
    const int xcd = g & 7;
    const int b = xcd >> 1;
    const int idx = ((g >> 3) << 1) | (xcd & 1);  // 0..255 per batch
    const int bm = idx >> 6;                      // c-tile (0..3)
    const int bn = idx & 63;                      // n-tile (0..63)

    const int tid = threadIdx.x;
    const int w = tid >> 6, l = tid & 63;
    const int lr = l & 15, lg = l >> 4;
    const int wr = w >> 1, wc = w & 1;            // wave quadrant: 64c x 32n

    const u16* Abase = Vb + (size_t)b * CIN * NTOK + (size_t)(bm * 128) * NTOK;
    const u16* Bbase = P + (size_t)b * NTOK * NTOK + (size_t)(bn * 64) * NTOK;

    f32x4 acc[4][2] = {};                         // [cf][nf]

    PVSTAGE(0, 0);
    for (int kt = 0; kt < 128; ++kt) {
        const int cur = kt & 1;
        __syncthreads();                          // staged tile `cur` ready (vmcnt drained)
        if (kt < 127) PVSTAGE(cur ^ 1, (kt + 1) * 32);

        s16x8 Af[4], Bf[2];
        const int swz = (lr & 3) << 3;
        #pragma unroll
        for (int cf = 0; cf < 4; ++cf)
            Af[cf] = *(const s16x8*)&As[cur][(wr * 64 + cf * 16 + lr) * 32 + ((lg * 8) ^ swz)];
        #pragma unroll
        for (int nf = 0; nf < 2; ++nf)
            Bf[nf] = *(const s16x8*)&Bs[cur][(wc * 32 + nf * 16 + lr) * 32 + ((lg * 8) ^ swz)];

        #pragma unroll
        for (int cf = 0; cf < 4; ++cf)
            #pragma unroll
            for (int nf = 0; nf < 2; ++nf)
                acc[cf][nf] = __builtin_amdgcn_mfma_f32_16x16x32_bf16(Af[cf], Bf[nf], acc[cf][nf], 0, 0, 0);
    }

    // epilogue: out = x_t + acc / den[n]
    const float* denb = den + (size_t)b * NTOK;
    float inv[2];
    #pragma unroll
    for (int nf = 0; nf < 2; ++nf) inv[nf] = 1.0f / denb[bn * 64 + wc * 32 + nf * 16 + lr];

    const float* xtp = x + (size_t)(b + NBATCH) * CIN * NTOK;
    float* op = out + (size_t)(b + NBATCH) * CIN * NTOK;
    #pragma unroll
    for (int cf = 0; cf < 4; ++cf) {
        #pragma unroll
        for (int nf = 0; nf < 2; ++nf) {
            #pragma unroll
            for (int r = 0; r < 4; ++r) {
                const int c = bm * 128 + wr * 64 + cf * 16 + lg * 4 + r;
                const int n = bn * 64 + wc * 32 + nf * 16 + lr;
                const size_t idx2 = (size_t)c * NTOK + n;
                op[idx2] = xtp[idx2] + acc[cf][nf][r] * inv[nf];
            }
        }
    }
}

extern "C" void kernel_launch(void* const* d_in, const int* in_sizes, int n_in,
                              void* d_out, int out_size, void* d_ws, size_t ws_size,
                              hipStream_t stream)
{
    (void)in_sizes; (void)n_in; (void)out_size; (void)ws_size;
    const float* x  = (const float*)d_in[0];
    const float* Wq = (const float*)d_in[1];
    const float* bq = (const float*)d_in[2];
    const float* Wk = (const float*)d_in[3];
    const float* bk = (const float*)d_in[4];
    const float* Wv = (const float*)d_in[5];
    const float* bv = (const float*)d_in[6];
    float* out = (float*)d_out;

    // ws layout (~148.1 MB): Qh 2MB | Kh 2MB | Vb 16MB | den 64KB | P 128MB
    u16* Qh = (u16*)d_ws;
    u16* Kh = Qh + (size_t)NBATCH * NTOK * OQK;
    u16* Vb = Kh + (size_t)NBATCH * NTOK * OQK;
    float* den = (float*)(Vb + (size_t)NBATCH * CIN * NTOK);
    u16* P  = (u16*)(den + (size_t)NBATCH * NTOK);

    proj_all<<<dim3(128, NBATCH), 512, 0, stream>>>(x, Wq, bq, Wk, bk, Wv, bv, Qh, Kh, Vb, out);
    qk_exp <<<1024, 256, 0, stream>>>(Qh, Kh, P, den);
    pv     <<<1024, 256, 0, stream>>>(x, Vb, P, den, out);
}

// Round 8
// 240.023 us; speedup vs baseline: 1.7000x; 1.1418x over previous
//
#include <hip/hip_runtime.h>
#include <hip/hip_bf16.h>

#define CIN 512
#define OQK 64
#define NBATCH 4
#define NTOK 4096

typedef float f32x4 __attribute__((ext_vector_type(4)));
typedef _Float16 f16x8 __attribute__((ext_vector_type(8)));
typedef short s16x8 __attribute__((ext_vector_type(8)));
typedef unsigned short u16;
typedef unsigned int u32;
typedef u32 u32x2 __attribute__((ext_vector_type(2)));
typedef u16 u16x4 __attribute__((ext_vector_type(4)));

__device__ inline u16 f2bf(float f) {
    unsigned u = __float_as_uint(f);
    u += 0x7fffu + ((u >> 16) & 1u);
    return (u16)(u >> 16);
}
__device__ inline u16 f2h_bits(float f) {
    _Float16 h = (_Float16)f;
    return __builtin_bit_cast(unsigned short, h);
}
__device__ inline f16x8 cvt8(const f32x4 a, const f32x4 b) {
    f16x8 r;
    #pragma unroll
    for (int j = 0; j < 4; ++j) { r[j] = (_Float16)a[j]; r[j + 4] = (_Float16)b[j]; }
    return r;
}

#define GLOAD16(gp, lp) __builtin_amdgcn_global_load_lds(                        \
    (const __attribute__((address_space(1))) void*)(gp),                         \
    (__attribute__((address_space(3))) void*)(lp), 16, 0, 0)

// ---------------- W f32 -> f16 pre-convert (into P-region alias, used only by proj) ----
__global__ __launch_bounds__(256) void wcvt(
    const float* __restrict__ Wq, const float* __restrict__ Wk,
    const float* __restrict__ Wv, u16* __restrict__ Wh)
{
    const size_t e0 = ((size_t)blockIdx.x * 256 + threadIdx.x) * 4;
    if (e0 >= 327680) return;
    const float* src; size_t off;
    if (e0 < 32768)      { src = Wq; off = e0; }
    else if (e0 < 65536) { src = Wk; off = e0 - 32768; }
    else                 { src = Wv; off = e0 - 65536; }
    f32x4 v = *reinterpret_cast<const f32x4*>(src + off);
    u16x4 h;
    #pragma unroll
    for (int j = 0; j < 4; ++j) h[j] = f2h_bits(v[j]);
    *reinterpret_cast<u16x4*>(Wh + e0) = h;
}

// ---------------- fused Q/K/V projections + x_s passthrough ----------------
// 512 thr. Per K-step: coalesced f32x4 x loads -> transposed LDS [n][c] (pitch 36),
// fragments read as contiguous b128. W operands are pre-converted f16 (direct 16B loads).
// waves 0-1: Q, 2-3: K, 4-7: V. Threads 0-255 stage x_s (+copy to out), 256-511 stage x_t.
__global__ __launch_bounds__(512, 2) void proj_all(
    const float* __restrict__ x,
    const float* __restrict__ bq, const float* __restrict__ bk, const float* __restrict__ bv,
    const u16* __restrict__ Wh,
    u16* __restrict__ Qh, u16* __restrict__ Kh, u16* __restrict__ Vb,
    float* __restrict__ out)
{
    __shared__ float Ls[32 * 36];
    __shared__ float Lt[32 * 36];

    const int nb = blockIdx.x;   // 128 panels of 32 tokens
    const int b  = blockIdx.y;   // 4
    const int tid = threadIdx.x;
    const int w = tid >> 6, l = tid & 63;
    const int lr = l & 15, lg = l >> 4;

    const int sg = tid >> 8;          // 0: x_s stager, 1: x_t stager
    const int st = tid & 255;
    const int c_l = st >> 3, nq = st & 7;
    const int n0 = nb * 32;

    const float* xs = x + (size_t)b * CIN * NTOK;
    const float* xt = x + (size_t)(b + NBATCH) * CIN * NTOK;
    const float* src = sg ? xt : xs;
    float* Lw = sg ? Lt : Ls;
    float* os = out + (size_t)b * CIN * NTOK;

    f32x4 acc[8][2] = {};   // V waves: [cf][fm]; Q/K waves use acc[0..3][0]

    f32x4 stg = *reinterpret_cast<const f32x4*>(src + (size_t)c_l * NTOK + n0 + nq * 4);

    for (int t = 0; t < 16; ++t) {
        const int c0 = t * 32;
        if (!sg)
            *reinterpret_cast<f32x4*>(os + (size_t)(c0 + c_l) * NTOK + n0 + nq * 4) = stg;
        #pragma unroll
        for (int j = 0; j < 4; ++j)
            Lw[(nq * 4 + j) * 36 + c_l] = stg[j];
        __syncthreads();

        f32x4 nxt;
        if (t < 15)
            nxt = *reinterpret_cast<const f32x4*>(src + (size_t)(c0 + 32 + c_l) * NTOK + n0 + nq * 4);

        if (w < 4) {
            const int qk = w >> 1, half = w & 1;
            const float* Lr = qk ? Lt : Ls;
            const u16* Wp = Wh + qk * 32768;
            f32x4 a0 = *reinterpret_cast<const f32x4*>(&Lr[(half * 16 + lr) * 36 + lg * 8]);
            f32x4 a1 = *reinterpret_cast<const f32x4*>(&Lr[(half * 16 + lr) * 36 + lg * 8 + 4]);
            f16x8 A = cvt8(a0, a1);
            #pragma unroll
            for (int of = 0; of < 4; ++of) {
                f16x8 B = *reinterpret_cast<const f16x8*>(&Wp[(size_t)(of * 16 + lr) * CIN + c0 + lg * 8]);
                acc[of][0] = __builtin_amdgcn_mfma_f32_16x16x32_f16(A, B, acc[of][0], 0, 0, 0);
            }
        } else {
            const int wv_ = w - 4;
            const u16* Wpv = Wh + 65536;
            f32x4 b00 = *reinterpret_cast<const f32x4*>(&Lt[lr * 36 + lg * 8]);
            f32x4 b01 = *reinterpret_cast<const f32x4*>(&Lt[lr * 36 + lg * 8 + 4]);
            f32x4 b10 = *reinterpret_cast<const f32x4*>(&Lt[(16 + lr) * 36 + lg * 8]);
            f32x4 b11 = *reinterpret_cast<const f32x4*>(&Lt[(16 + lr) * 36 + lg * 8 + 4]);
            f16x8 B0 = cvt8(b00, b01);
            f16x8 B1 = cvt8(b10, b11);
            #pragma unroll
            for (int cf = 0; cf < 8; ++cf) {
                f16x8 A = *reinterpret_cast<const f16x8*>(&Wpv[(size_t)(wv_ * 128 + cf * 16 + lr) * CIN + c0 + lg * 8]);
                acc[cf][0] = __builtin_amdgcn_mfma_f32_16x16x32_f16(A, B0, acc[cf][0], 0, 0, 0);
                acc[cf][1] = __builtin_amdgcn_mfma_f32_16x16x32_f16(A, B1, acc[cf][1], 0, 0, 0);
            }
        }
        __syncthreads();
        stg = nxt;
    }

    if (w < 4) {
        const int qk = w >> 1, half = w & 1;
        const float* bias = qk ? bk : bq;
        u16* outp = qk ? Kh : Qh;
        #pragma unroll
        for (int of = 0; of < 4; ++of) {
            const int o = of * 16 + lr;
            const float bb_ = bias[o];
            #pragma unroll
            for (int r = 0; r < 4; ++r) {
                const int nn = nb * 32 + half * 16 + lg * 4 + r;
                outp[((size_t)b * NTOK + nn) * OQK + o] = f2h_bits(acc[of][0][r] + bb_);
            }
        }
    } else {
        const int wv_ = w - 4;
        #pragma unroll
        for (int cf = 0; cf < 8; ++cf) {
            #pragma unroll
            for (int fm = 0; fm < 2; ++fm) {
                #pragma unroll
                for (int r = 0; r < 4; ++r) {
                    const int c  = wv_ * 128 + cf * 16 + lg * 4 + r;
                    const int mm = nb * 32 + fm * 16 + lr;
                    Vb[((size_t)b * CIN + c) * NTOK + mm] = f2bf(acc[cf][fm][r] + bv[c]);
                }
            }
        }
    }
}

// ---------------- pass S: P = exp(K Q^T) (bf16, [b][n][m]) + exact den ----------------
#define SLOADK(mt, KF)                                                          \
  { _Pragma("unroll")                                                           \
    for (int mf_ = 0; mf_ < 4; ++mf_) {                                         \
      const u16* kp = Kbase + (size_t)((mt) * 64 + mf_ * 16 + lr) * OQK + lg * 8; \
      KF[mf_][0] = *reinterpret_cast<const f16x8*>(kp);                         \
      KF[mf_][1] = *reinterpret_cast<const f16x8*>(kp + 32);                    \
    } }

#define STILE(mt, KF)                                                           \
  { _Pragma("unroll")                                                           \
    for (int mf_ = 0; mf_ < 4; ++mf_) {                                         \
      f32x4 s_ = {};                                                            \
      s_ = __builtin_amdgcn_mfma_f32_16x16x32_f16(KF[mf_][0], Bq0, s_, 0, 0, 0);\
      s_ = __builtin_amdgcn_mfma_f32_16x16x32_f16(KF[mf_][1], Bq1, s_, 0, 0, 0);\
      float p0 = __expf(s_[0]), p1 = __expf(s_[1]);                             \
      float p2 = __expf(s_[2]), p3 = __expf(s_[3]);                             \
      denl += (p0 + p1) + (p2 + p3);                                            \
      u32x2 pk;                                                                 \
      pk[0] = (u32)f2bf(p0) | ((u32)f2bf(p1) << 16);                            \
      pk[1] = (u32)f2bf(p2) | ((u32)f2bf(p3) << 16);                            \
      *reinterpret_cast<u32x2*>(Pp + (size_t)n * NTOK + (mt) * 64 + mf_ * 16 + lg * 4) = pk; \
    } }

__global__ __launch_bounds__(256, 4) void qk_exp(
    const u16* __restrict__ Qh, const u16* __restrict__ Kh,
    u16* __restrict__ P, float* __restrict__ den)
{
    __shared__ float dpart[4][16];
    const int g = blockIdx.x;
    const int xcd = g & 7;
    const int b = xcd >> 1;
    const int grp = ((g >> 3) << 1) | (xcd & 1);   // 16-row group (0..255)

    const int tid = threadIdx.x;
    const int w = tid >> 6, l = tid & 63;
    const int lr = l & 15, lg = l >> 4;

    const int n = grp * 16 + lr;
    const int mbase = w * 1024;                    // wave's m-quarter
    const u16* Kbase = Kh + ((size_t)b * NTOK + mbase) * OQK;
    u16* Pp = P + (size_t)b * NTOK * NTOK + mbase;

    f16x8 Bq0, Bq1;
    {
        const u16* qp = Qh + ((size_t)b * NTOK + n) * OQK + lg * 8;
        Bq0 = *reinterpret_cast<const f16x8*>(qp);
        Bq1 = *reinterpret_cast<const f16x8*>(qp + 32);
    }

    float denl = 0.f;
    f16x8 KfA[4][2], KfB[4][2];

    SLOADK(0, KfA);
    for (int mt = 0; mt < 16; mt += 2) {
        SLOADK(mt + 1, KfB);
        STILE(mt, KfA);
        if (mt + 2 < 16) SLOADK(mt + 2, KfA);
        STILE(mt + 1, KfB);
    }

    denl += __shfl_xor(denl, 16);
    denl += __shfl_xor(denl, 32);
    if (l < 16) dpart[w][l] = denl;
    __syncthreads();
    if (tid < 16)
        den[(size_t)b * NTOK + grp * 16 + tid] =
            (dpart[0][tid] + dpart[1][tid]) + (dpart[2][tid] + dpart[3][tid]);
}

// ---------------- pass PV: out = x_t + (V P^T) / den ----------------
// 128x128 tile, 4 waves (64x64 each, 16 MFMA : 8 ds_read_b128 per K-step).
// 4 LDS buffers, 2-tile-deep prefetch via global_load_lds + counted vmcnt(8)
// (never drained to 0 in the loop), 1 barrier per K-step. Grid 512 = 2 blocks/CU.

#define PVSTAGE(BUF, m0)                                                        \
  { _Pragma("unroll")                                                           \
    for (int i_ = 0; i_ < 2; ++i_) {                                            \
      const int chunk_ = i_ * 256 + tid;                                        \
      const int row_ = chunk_ >> 2;                                             \
      const int sl_ = (chunk_ & 3) ^ (row_ & 3);                                \
      GLOAD16(Abase + (size_t)row_ * NTOK + (m0) + sl_ * 8,                     \
              &AS[(BUF) * 4096 + (i_ * 256 + w * 64) * 8]);                     \
    }                                                                           \
    _Pragma("unroll")                                                           \
    for (int j_ = 0; j_ < 2; ++j_) {                                            \
      const int chunk_ = j_ * 256 + tid;                                        \
      const int row_ = chunk_ >> 2;                                             \
      const int sl_ = (chunk_ & 3) ^ (row_ & 3);                                \
      GLOAD16(Bbase + (size_t)row_ * NTOK + (m0) + sl_ * 8,                     \
              &BS[(BUF) * 4096 + (j_ * 256 + w * 64) * 8]);                     \
    } }

#define PVBODY(CUR, PRE, kt)                                                    \
  {                                                                             \
    if ((kt) + 2 < 128) PVSTAGE(PRE, ((kt) + 2) * 32);                          \
    asm volatile("s_waitcnt vmcnt(8)" ::: "memory");                            \
    __builtin_amdgcn_s_barrier();                                               \
    s16x8 Af[4], Bf[4];                                                         \
    const int swz_ = (lr & 3) << 3;                                             \
    _Pragma("unroll")                                                           \
    for (int f_ = 0; f_ < 4; ++f_) {                                            \
      Af[f_] = *(const s16x8*)&AS[(CUR) * 4096 + (wr * 64 + f_ * 16 + lr) * 32 + ((lg * 8) ^ swz_)]; \
      Bf[f_] = *(const s16x8*)&BS[(CUR) * 4096 + (wc * 64 + f_ * 16 + lr) * 32 + ((lg * 8) ^ swz_)]; \
    }                                                                           \
    __builtin_amdgcn_s_setprio(1);                                              \
    _Pragma("unroll")                                                           \
    for (int cf_ = 0; cf_ < 4; ++cf_)                                           \
      _Pragma("unroll")                                                         \
      for (int nf_ = 0; nf_ < 4; ++nf_)                                         \
        acc[cf_][nf_] = __builtin_amdgcn_mfma_f32_16x16x32_bf16(Af[cf_], Bf[nf_], acc[cf_][nf_], 0, 0, 0); \
    __builtin_amdgcn_s_setprio(0);                                              \
  }

__global__ __launch_bounds__(256, 2) void pv(
    const float* __restrict__ x, const u16* __restrict__ Vb,
    const u16* __restrict__ P, const float* __restrict__ den,
    float* __restrict__ out)
{
    __shared__ u16 AS[4 * 4096];   // 4 bufs x 128rows x 32k  (V)
    __shared__ u16 BS[4 * 4096];   // 4 bufs x 128rows x 32k  (P)

    const int g = blockIdx.x;
    const int xcd = g & 7;
    const int b = xcd >> 1;
    const int idx = ((g >> 3) << 1) | (xcd & 1);  // 0..127 per batch
    const int bm = idx >> 5;                      // c-tile (0..3)
    const int bn = idx & 31;                      // n-tile (0..31)

    const int tid = threadIdx.x;
    const int w = tid >> 6, l = tid & 63;
    const int lr = l & 15, lg = l >> 4;
    const int wr = w >> 1, wc = w & 1;            // wave quadrant: 64c x 64n

    const u16* Abase = Vb + (size_t)b * CIN * NTOK + (size_t)(bm * 128) * NTOK;
    const u16* Bbase = P + (size_t)b * NTOK * NTOK + (size_t)(bn * 128) * NTOK;

    f32x4 acc[4][4] = {};                         // [cf][nf]

    PVSTAGE(0, 0);
    PVSTAGE(1, 32);
    for (int kt = 0; kt < 128; kt += 4) {
        PVBODY(0, 2, kt);
        PVBODY(1, 3, kt + 1);
        PVBODY(2, 0, kt + 2);
        PVBODY(3, 1, kt + 3);
    }

    // epilogue: out = x_t + acc / den[n]
    const float* denb = den + (size_t)b * NTOK;
    float inv[4];
    #pragma unroll
    for (int nf = 0; nf < 4; ++nf) inv[nf] = 1.0f / denb[bn * 128 + wc * 64 + nf * 16 + lr];

    const float* xtp = x + (size_t)(b + NBATCH) * CIN * NTOK;
    float* op = out + (size_t)(b + NBATCH) * CIN * NTOK;
    #pragma unroll
    for (int cf = 0; cf < 4; ++cf) {
        #pragma unroll
        for (int nf = 0; nf < 4; ++nf) {
            #pragma unroll
            for (int r = 0; r < 4; ++r) {
                const int c = bm * 128 + wr * 64 + cf * 16 + lg * 4 + r;
                const int n = bn * 128 + wc * 64 + nf * 16 + lr;
                const size_t idx2 = (size_t)c * NTOK + n;
                op[idx2] = xtp[idx2] + acc[cf][nf][r] * inv[nf];
            }
        }
    }
}

extern "C" void kernel_launch(void* const* d_in, const int* in_sizes, int n_in,
                              void* d_out, int out_size, void* d_ws, size_t ws_size,
                              hipStream_t stream)
{
    (void)in_sizes; (void)n_in; (void)out_size; (void)ws_size;
    const float* x  = (const float*)d_in[0];
    const float* Wq = (const float*)d_in[1];
    const float* bq = (const float*)d_in[2];
    const float* Wk = (const float*)d_in[3];
    const float* bk = (const float*)d_in[4];
    const float* Wv = (const float*)d_in[5];
    const float* bv = (const float*)d_in[6];
    float* out = (float*)d_out;

    // ws layout (~148.1 MB): Qh 2MB | Kh 2MB | Vb 16MB | den 64KB | P 128MB
    // Wh (f16 weights, 640KB) aliases the head of P: used only by proj_all,
    // before qk_exp overwrites P.
    u16* Qh = (u16*)d_ws;
    u16* Kh = Qh + (size_t)NBATCH * NTOK * OQK;
    u16* Vb = Kh + (size_t)NBATCH * NTOK * OQK;
    float* den = (float*)(Vb + (size_t)NBATCH * CIN * NTOK);
    u16* P  = (u16*)(den + (size_t)NBATCH * NTOK);
    u16* Wh = P;

    wcvt    <<<320, 256, 0, stream>>>(Wq, Wk, Wv, Wh);
    proj_all<<<dim3(128, NBATCH), 512, 0, stream>>>(x, bq, bk, bv, Wh, Qh, Kh, Vb, out);
    qk_exp  <<<1024, 256, 0, stream>>>(Qh, Kh, P, den);
    pv      <<<512, 256, 0, stream>>>(x, Vb, P, den, out);
}

// Round 9
// 222.470 us; speedup vs baseline: 1.8342x; 1.0789x over previous
//
#include <hip/hip_runtime.h>
#include <hip/hip_bf16.h>

#define CIN 512
#define OQK 64
#define NBATCH 4
#define NTOK 4096

typedef float f32x4 __attribute__((ext_vector_type(4)));
typedef _Float16 f16x8 __attribute__((ext_vector_type(8)));
typedef short s16x8 __attribute__((ext_vector_type(8)));
typedef unsigned short u16;
typedef unsigned int u32;
typedef u32 u32x2 __attribute__((ext_vector_type(2)));
typedef u16 u16x4 __attribute__((ext_vector_type(4)));

__device__ inline u16 f2bf(float f) {
    unsigned u = __float_as_uint(f);
    u += 0x7fffu + ((u >> 16) & 1u);
    return (u16)(u >> 16);
}
__device__ inline u16 f2h_bits(float f) {
    _Float16 h = (_Float16)f;
    return __builtin_bit_cast(unsigned short, h);
}
__device__ inline f16x8 cvt8(const f32x4 a, const f32x4 b) {
    f16x8 r;
    #pragma unroll
    for (int j = 0; j < 4; ++j) { r[j] = (_Float16)a[j]; r[j + 4] = (_Float16)b[j]; }
    return r;
}

#define GLOAD16(gp, lp) __builtin_amdgcn_global_load_lds(                        \
    (const __attribute__((address_space(1))) void*)(gp),                         \
    (__attribute__((address_space(3))) void*)(lp), 16, 0, 0)

// ---------------- W f32 -> f16 pre-convert (into P-region alias) ----------------
__global__ __launch_bounds__(256) void wcvt(
    const float* __restrict__ Wq, const float* __restrict__ Wk,
    const float* __restrict__ Wv, u16* __restrict__ Wh)
{
    const size_t e0 = ((size_t)blockIdx.x * 256 + threadIdx.x) * 4;
    if (e0 >= 327680) return;
    const float* src; size_t off;
    if (e0 < 32768)      { src = Wq; off = e0; }
    else if (e0 < 65536) { src = Wk; off = e0 - 32768; }
    else                 { src = Wv; off = e0 - 65536; }
    f32x4 v = *reinterpret_cast<const f32x4*>(src + off);
    u16x4 h;
    #pragma unroll
    for (int j = 0; j < 4; ++j) h[j] = f2h_bits(v[j]);
    *reinterpret_cast<u16x4*>(Wh + e0) = h;
}

// ---------------- fused Q/K/V projections + x_s passthrough ----------------
// 512 thr, double-buffered LDS transpose, ONE raw barrier per sub-tile
// (lgkmcnt(0) only -- x prefetch + out stores stay in flight across barriers),
// W fragments prefetched one sub-tile ahead in static register double-buffers.
// waves 0-1: Q (+ x_s copy to out), 2-3: K, 4-7: V. Threads 0-255 stage x_s
// into Ls, threads 256-511 stage x_t into Lt.
__global__ __launch_bounds__(512, 2) void proj_all(
    const float* __restrict__ x,
    const float* __restrict__ bq, const float* __restrict__ bk, const float* __restrict__ bv,
    const u16* __restrict__ Wh,
    u16* __restrict__ Qh, u16* __restrict__ Kh, u16* __restrict__ Vb,
    float* __restrict__ out)
{
    __shared__ float Ls[2][32 * 36];
    __shared__ float Lt[2][32 * 36];

    const int nb = blockIdx.x;   // 128 panels of 32 tokens
    const int b  = blockIdx.y;   // 4
    const int tid = threadIdx.x;
    const int w = tid >> 6, l = tid & 63;
    const int lr = l & 15, lg = l >> 4;
    const int st = tid & 255;
    const int c_l = st >> 3, nq = st & 7;
    const int n0 = nb * 32;

    const float* xs = x + (size_t)b * CIN * NTOK;
    const float* xt = x + (size_t)(b + NBATCH) * CIN * NTOK;
    float* os = out + (size_t)b * CIN * NTOK;

#define PBAR() { asm volatile("s_waitcnt lgkmcnt(0)" ::: "memory");             \
                 __builtin_amdgcn_s_barrier();                                  \
                 __builtin_amdgcn_sched_barrier(0); }

    if (w < 4) {
        // ======== Q/K waves; stage x_s -> Ls; copy x_s -> out ========
        const int qk = w >> 1, half = w & 1;
        const u16* Wp = Wh + qk * 32768;

        f32x4 acc[4] = {};
        f16x8 WA[4], WB[4];
        f32x4 sA, sB;

#define QK_PLD(t) (*reinterpret_cast<const f32x4*>(xs + (size_t)((t) * 32 + c_l) * NTOK + n0 + nq * 4))
#define QK_PST(BUF, t, S) {                                                      \
    *reinterpret_cast<f32x4*>(os + (size_t)((t) * 32 + c_l) * NTOK + n0 + nq * 4) = S; \
    _Pragma("unroll") for (int j_ = 0; j_ < 4; ++j_) Ls[BUF][(nq * 4 + j_) * 36 + c_l] = S[j_]; }
#define QK_WLD(WF, t) { _Pragma("unroll") for (int of_ = 0; of_ < 4; ++of_)      \
    WF[of_] = *reinterpret_cast<const f16x8*>(&Wp[(size_t)(of_ * 16 + lr) * CIN + (t) * 32 + lg * 8]); }
#define QK_CMP(BUF, WF) {                                                        \
    const float* Lr_ = qk ? &Lt[BUF][0] : &Ls[BUF][0];                           \
    f32x4 a0_ = *reinterpret_cast<const f32x4*>(&Lr_[(half * 16 + lr) * 36 + lg * 8]);     \
    f32x4 a1_ = *reinterpret_cast<const f32x4*>(&Lr_[(half * 16 + lr) * 36 + lg * 8 + 4]); \
    f16x8 A_ = cvt8(a0_, a1_);                                                   \
    _Pragma("unroll") for (int of_ = 0; of_ < 4; ++of_)                          \
        acc[of_] = __builtin_amdgcn_mfma_f32_16x16x32_f16(A_, WF[of_], acc[of_], 0, 0, 0); }

        sA = QK_PLD(0); QK_PST(0, 0, sA);
        sB = QK_PLD(1);
        QK_WLD(WA, 0);
        PBAR();
        for (int t = 0; t < 16; t += 2) {
            QK_WLD(WB, t + 1);
            QK_CMP(0, WA);
            QK_PST(1, t + 1, sB);
            if (t < 14) sA = QK_PLD(t + 2);
            PBAR();
            if (t < 14) QK_WLD(WA, t + 2);
            QK_CMP(1, WB);
            if (t < 14) { QK_PST(0, t + 2, sA); sB = QK_PLD(t + 3); }
            PBAR();
        }

        const float* bias = qk ? bk : bq;
        u16* outp = qk ? Kh : Qh;
        #pragma unroll
        for (int of = 0; of < 4; ++of) {
            const int o = of * 16 + lr;
            const float bb_ = bias[o];
            #pragma unroll
            for (int r = 0; r < 4; ++r) {
                const int nn = nb * 32 + half * 16 + lg * 4 + r;
                outp[((size_t)b * NTOK + nn) * OQK + o] = f2h_bits(acc[of][r] + bb_);
            }
        }
    } else {
        // ======== V waves; stage x_t -> Lt ========
        const int wv_ = w - 4;
        const u16* Wpv = Wh + 65536;

        f32x4 acc[8][2] = {};
        f16x8 WA[8], WB[8];
        f32x4 sA, sB;

#define V_PLD(t) (*reinterpret_cast<const f32x4*>(xt + (size_t)((t) * 32 + c_l) * NTOK + n0 + nq * 4))
#define V_PST(BUF, t, S) {                                                       \
    _Pragma("unroll") for (int j_ = 0; j_ < 4; ++j_) Lt[BUF][(nq * 4 + j_) * 36 + c_l] = S[j_]; }
#define V_WLD(WF, t) { _Pragma("unroll") for (int cf_ = 0; cf_ < 8; ++cf_)       \
    WF[cf_] = *reinterpret_cast<const f16x8*>(&Wpv[(size_t)(wv_ * 128 + cf_ * 16 + lr) * CIN + (t) * 32 + lg * 8]); }
#define V_CMP(BUF, WF) {                                                         \
    f32x4 b00_ = *reinterpret_cast<const f32x4*>(&Lt[BUF][lr * 36 + lg * 8]);            \
    f32x4 b01_ = *reinterpret_cast<const f32x4*>(&Lt[BUF][lr * 36 + lg * 8 + 4]);        \
    f32x4 b10_ = *reinterpret_cast<const f32x4*>(&Lt[BUF][(16 + lr) * 36 + lg * 8]);     \
    f32x4 b11_ = *reinterpret_cast<const f32x4*>(&Lt[BUF][(16 + lr) * 36 + lg * 8 + 4]); \
    f16x8 B0_ = cvt8(b00_, b01_);                                                \
    f16x8 B1_ = cvt8(b10_, b11_);                                                \
    _Pragma("unroll") for (int cf_ = 0; cf_ < 8; ++cf_) {                        \
        acc[cf_][0] = __builtin_amdgcn_mfma_f32_16x16x32_f16(WF[cf_], B0_, acc[cf_][0], 0, 0, 0); \
        acc[cf_][1] = __builtin_amdgcn_mfma_f32_16x16x32_f16(WF[cf_], B1_, acc[cf_][1], 0, 0, 0); } }

        sA = V_PLD(0); V_PST(0, 0, sA);
        sB = V_PLD(1);
        V_WLD(WA, 0);
        PBAR();
        for (int t = 0; t < 16; t += 2) {
            V_WLD(WB, t + 1);
            V_CMP(0, WA);
            V_PST(1, t + 1, sB);
            if (t < 14) sA = V_PLD(t + 2);
            PBAR();
            if (t < 14) V_WLD(WA, t + 2);
            V_CMP(1, WB);
            if (t < 14) { V_PST(0, t + 2, sA); sB = V_PLD(t + 3); }
            PBAR();
        }

        #pragma unroll
        for (int cf = 0; cf < 8; ++cf) {
            #pragma unroll
            for (int fm = 0; fm < 2; ++fm) {
                #pragma unroll
                for (int r = 0; r < 4; ++r) {
                    const int c  = wv_ * 128 + cf * 16 + lg * 4 + r;
                    const int mm = nb * 32 + fm * 16 + lr;
                    Vb[((size_t)b * CIN + c) * NTOK + mm] = f2bf(acc[cf][fm][r] + bv[c]);
                }
            }
        }
    }
}

// ---------------- pass S: P = exp(K Q^T) (bf16, [b][n][m]) + exact den ----------------
#define SLOADK(mt, KF)                                                          \
  { _Pragma("unroll")                                                           \
    for (int mf_ = 0; mf_ < 4; ++mf_) {                                         \
      const u16* kp = Kbase + (size_t)((mt) * 64 + mf_ * 16 + lr) * OQK + lg * 8; \
      KF[mf_][0] = *reinterpret_cast<const f16x8*>(kp);                         \
      KF[mf_][1] = *reinterpret_cast<const f16x8*>(kp + 32);                    \
    } }

#define STILE(mt, KF)                                                           \
  { _Pragma("unroll")                                                           \
    for (int mf_ = 0; mf_ < 4; ++mf_) {                                         \
      f32x4 s_ = {};                                                            \
      s_ = __builtin_amdgcn_mfma_f32_16x16x32_f16(KF[mf_][0], Bq0, s_, 0, 0, 0);\
      s_ = __builtin_amdgcn_mfma_f32_16x16x32_f16(KF[mf_][1], Bq1, s_, 0, 0, 0);\
      float p0 = __expf(s_[0]), p1 = __expf(s_[1]);                             \
      float p2 = __expf(s_[2]), p3 = __expf(s_[3]);                             \
      denl += (p0 + p1) + (p2 + p3);                                            \
      u32x2 pk;                                                                 \
      pk[0] = (u32)f2bf(p0) | ((u32)f2bf(p1) << 16);                            \
      pk[1] = (u32)f2bf(p2) | ((u32)f2bf(p3) << 16);                            \
      *reinterpret_cast<u32x2*>(Pp + (size_t)n * NTOK + (mt) * 64 + mf_ * 16 + lg * 4) = pk; \
    } }

__global__ __launch_bounds__(256, 4) void qk_exp(
    const u16* __restrict__ Qh, const u16* __restrict__ Kh,
    u16* __restrict__ P, float* __restrict__ den)
{
    __shared__ float dpart[4][16];
    const int g = blockIdx.x;
    const int xcd = g & 7;
    const int b = xcd >> 1;
    const int grp = ((g >> 3) << 1) | (xcd & 1);   // 16-row group (0..255)

    const int tid = threadIdx.x;
    const int w = tid >> 6, l = tid & 63;
    const int lr = l & 15, lg = l >> 4;

    const int n = grp * 16 + lr;
    const int mbase = w * 1024;                    // wave's m-quarter
    const u16* Kbase = Kh + ((size_t)b * NTOK + mbase) * OQK;
    u16* Pp = P + (size_t)b * NTOK * NTOK + mbase;

    f16x8 Bq0, Bq1;
    {
        const u16* qp = Qh + ((size_t)b * NTOK + n) * OQK + lg * 8;
        Bq0 = *reinterpret_cast<const f16x8*>(qp);
        Bq1 = *reinterpret_cast<const f16x8*>(qp + 32);
    }

    float denl = 0.f;
    f16x8 KfA[4][2], KfB[4][2];

    SLOADK(0, KfA);
    for (int mt = 0; mt < 16; mt += 2) {
        SLOADK(mt + 1, KfB);
        STILE(mt, KfA);
        if (mt + 2 < 16) SLOADK(mt + 2, KfA);
        STILE(mt + 1, KfB);
    }

    denl += __shfl_xor(denl, 16);
    denl += __shfl_xor(denl, 32);
    if (l < 16) dpart[w][l] = denl;
    __syncthreads();
    if (tid < 16)
        den[(size_t)b * NTOK + grp * 16 + tid] =
            (dpart[0][tid] + dpart[1][tid]) + (dpart[2][tid] + dpart[3][tid]);
}

// ---------------- pass PV: out = x_t + (V P^T) / den ----------------
// 128x128 tile, 4 waves (64c x 64n each). 4 LDS buffers, 3-tile-deep prefetch,
// stage issued AFTER the barrier (safe buffer reuse), counted vmcnt(8) with a
// peeled 8/8/4/0 tail. Swizzle uses ((row>>1)&3) -> conflict-free b128 reads.

#define PVSTAGE(BUF, m0)                                                        \
  { _Pragma("unroll")                                                           \
    for (int i_ = 0; i_ < 2; ++i_) {                                            \
      const int chunk_ = i_ * 256 + tid;                                        \
      const int row_ = chunk_ >> 2;                                             \
      const int sl_ = (chunk_ & 3) ^ ((row_ >> 1) & 3);                         \
      GLOAD16(Abase + (size_t)row_ * NTOK + (m0) + sl_ * 8,                     \
              &AS[(BUF) * 4096 + chunk_ * 8]);                                  \
    }                                                                           \
    _Pragma("unroll")                                                           \
    for (int j_ = 0; j_ < 2; ++j_) {                                            \
      const int chunk_ = j_ * 256 + tid;                                        \
      const int row_ = chunk_ >> 2;                                             \
      const int sl_ = (chunk_ & 3) ^ ((row_ >> 1) & 3);                         \
      GLOAD16(Bbase + (size_t)row_ * NTOK + (m0) + sl_ * 8,                     \
              &BS[(BUF) * 4096 + chunk_ * 8]);                                  \
    } }

#define PVBODY(CUR, kt, DOSTAGE, VM)                                            \
  {                                                                             \
    asm volatile("s_waitcnt vmcnt(" VM ")" ::: "memory");                       \
    __builtin_amdgcn_s_barrier();                                               \
    if (DOSTAGE) PVSTAGE(((kt) + 3) & 3, ((kt) + 3) * 32);                      \
    s16x8 Af[4], Bf[4];                                                         \
    const int swz_ = ((lr >> 1) & 3) << 3;                                      \
    _Pragma("unroll")                                                           \
    for (int f_ = 0; f_ < 4; ++f_) {                                            \
      Af[f_] = *(const s16x8*)&AS[(CUR) * 4096 + (wr * 64 + f_ * 16 + lr) * 32 + ((lg * 8) ^ swz_)]; \
      Bf[f_] = *(const s16x8*)&BS[(CUR) * 4096 + (wc * 64 + f_ * 16 + lr) * 32 + ((lg * 8) ^ swz_)]; \
    }                                                                           \
    __builtin_amdgcn_s_setprio(1);                                              \
    _Pragma("unroll")                                                           \
    for (int cf_ = 0; cf_ < 4; ++cf_)                                           \
      _Pragma("unroll")                                                         \
      for (int nf_ = 0; nf_ < 4; ++nf_)                                         \
        acc[cf_][nf_] = __builtin_amdgcn_mfma_f32_16x16x32_bf16(Af[cf_], Bf[nf_], acc[cf_][nf_], 0, 0, 0); \
    __builtin_amdgcn_s_setprio(0);                                              \
  }

__global__ __launch_bounds__(256, 2) void pv(
    const float* __restrict__ x, const u16* __restrict__ Vb,
    const u16* __restrict__ P, const float* __restrict__ den,
    float* __restrict__ out)
{
    __shared__ u16 AS[4 * 4096];   // 4 bufs x 128rows x 32k  (V)
    __shared__ u16 BS[4 * 4096];   // 4 bufs x 128rows x 32k  (P)

    const int g = blockIdx.x;
    const int xcd = g & 7;
    const int b = xcd >> 1;
    const int idx = ((g >> 3) << 1) | (xcd & 1);  // 0..127 per batch
    const int bm = idx >> 5;                      // c-tile (0..3)
    const int bn = idx & 31;                      // n-tile (0..31)

    const int tid = threadIdx.x;
    const int w = tid >> 6, l = tid & 63;
    const int lr = l & 15, lg = l >> 4;
    const int wr = w >> 1, wc = w & 1;            // wave quadrant: 64c x 64n

    const u16* Abase = Vb + (size_t)b * CIN * NTOK + (size_t)(bm * 128) * NTOK;
    const u16* Bbase = P + (size_t)b * NTOK * NTOK + (size_t)(bn * 128) * NTOK;

    f32x4 acc[4][4] = {};                         // [cf][nf]

    PVSTAGE(0, 0);
    PVSTAGE(1, 32);
    PVSTAGE(2, 64);
    for (int kt2 = 0; kt2 < 124; kt2 += 4) {
        PVBODY(0, kt2 + 0, true, "8");
        PVBODY(1, kt2 + 1, true, "8");
        PVBODY(2, kt2 + 2, true, "8");
        PVBODY(3, kt2 + 3, true, "8");
    }
    PVBODY(0, 124, true,  "8");
    PVBODY(1, 125, false, "8");
    PVBODY(2, 126, false, "4");
    PVBODY(3, 127, false, "0");

    // epilogue: out = x_t + acc / den[n]
    const float* denb = den + (size_t)b * NTOK;
    float inv[4];
    #pragma unroll
    for (int nf = 0; nf < 4; ++nf) inv[nf] = 1.0f / denb[bn * 128 + wc * 64 + nf * 16 + lr];

    const float* xtp = x + (size_t)(b + NBATCH) * CIN * NTOK;
    float* op = out + (size_t)(b + NBATCH) * CIN * NTOK;
    #pragma unroll
    for (int cf = 0; cf < 4; ++cf) {
        #pragma unroll
        for (int nf = 0; nf < 4; ++nf) {
            #pragma unroll
            for (int r = 0; r < 4; ++r) {
                const int c = bm * 128 + wr * 64 + cf * 16 + lg * 4 + r;
                const int n = bn * 128 + wc * 64 + nf * 16 + lr;
                const size_t idx2 = (size_t)c * NTOK + n;
                op[idx2] = xtp[idx2] + acc[cf][nf][r] * inv[nf];
            }
        }
    }
}

extern "C" void kernel_launch(void* const* d_in, const int* in_sizes, int n_in,
                              void* d_out, int out_size, void* d_ws, size_t ws_size,
                              hipStream_t stream)
{
    (void)in_sizes; (void)n_in; (void)out_size; (void)ws_size;
    const float* x  = (const float*)d_in[0];
    const float* Wq = (const float*)d_in[1];
    const float* bq = (const float*)d_in[2];
    const float* Wk = (const float*)d_in[3];
    const float* bk = (const float*)d_in[4];
    const float* Wv = (const float*)d_in[5];
    const float* bv = (const float*)d_in[6];
    float* out = (float*)d_out;

    // ws layout (~148.1 MB): Qh 2MB | Kh 2MB | Vb 16MB | den 64KB | P 128MB
    // Wh (f16 weights, 640KB) aliases the head of P (dead before qk_exp writes P).
    u16* Qh = (u16*)d_ws;
    u16* Kh = Qh + (size_t)NBATCH * NTOK * OQK;
    u16* Vb = Kh + (size_t)NBATCH * NTOK * OQK;
    float* den = (float*)(Vb + (size_t)NBATCH * CIN * NTOK);
    u16* P  = (u16*)(den + (size_t)NBATCH * NTOK);
    u16* Wh = P;

    wcvt    <<<320, 256, 0, stream>>>(Wq, Wk, Wv, Wh);
    proj_all<<<dim3(128, NBATCH), 512, 0, stream>>>(x, bq, bk, bv, Wh, Qh, Kh, Vb, out);
    qk_exp  <<<1024, 256, 0, stream>>>(Qh, Kh, P, den);
    pv      <<<512, 256, 0, stream>>>(x, Vb, P, den, out);
}